// Round 5
// baseline (300.055 us; speedup 1.0000x reference)
//
#include <hip/hip_runtime.h>

#define N_NODES 100000
#define N_EDGES 1600000
#define IN_C 128
#define HID_C 64
#define OUT_C 32

#define NBUCK 782        // ceil(100000 / 128) buckets of 128 nodes
#define NBLK_B 512       // edge-chunk blocks for bucket count/scatter
#define CHUNK 3125       // N_EDGES / NBLK_B
#define BSTRIDE 1024     // padded stride for bcnt/off tables
#define MAXPT 12         // per-thread reg capacity in CSR build (3072/bucket)

#define GROWS 256        // rows per GEMM block
#define GEMM_BLKS 391    // ceil(N_NODES / GROWS)

// ---------------- K1: per-block coarse bucket histogram (LDS atomics only) ----------------

__global__ __launch_bounds__(256) void k_bucket_count(const int* __restrict__ dst,
                                                      int* __restrict__ bcnt) {
    __shared__ int h[NBUCK];
    int t = threadIdx.x;
    for (int b = t; b < NBUCK; b += 256) h[b] = 0;
    __syncthreads();
    int base = blockIdx.x * CHUNK, end = base + CHUNK;
#pragma unroll
    for (int it = 0; it < 13; ++it) {
        int i = base + it * 256 + t;
        if (i < end) atomicAdd(&h[dst[i] >> 7], 1);
    }
    __syncthreads();
    for (int b = t; b < NBUCK; b += 256) bcnt[blockIdx.x * BSTRIDE + b] = h[b];
}

// ---------------- K2a: per-bucket column scan over 512 blocks -> off, total ----------------

__global__ __launch_bounds__(256) void k_col_scan(const int* __restrict__ bcnt,
                                                  int* __restrict__ off,
                                                  int* __restrict__ total) {
    __shared__ int v[512];
    __shared__ int ps[256];
    int t = threadIdx.x, b = blockIdx.x;
    v[t]       = bcnt[t * BSTRIDE + b];
    v[t + 256] = bcnt[(t + 256) * BSTRIDE + b];
    __syncthreads();
    int a = v[2 * t], c = v[2 * t + 1];
    ps[t] = a + c;
    __syncthreads();
    for (int o = 1; o < 256; o <<= 1) {
        int u = (t >= o) ? ps[t - o] : 0;
        __syncthreads();
        ps[t] += u;
        __syncthreads();
    }
    int ex = (t > 0) ? ps[t - 1] : 0;  // exclusive prefix (local to bucket)
    off[(2 * t) * BSTRIDE + b]     = ex;
    off[(2 * t + 1) * BSTRIDE + b] = ex + a;
    if (t == 255) total[b] = ps[255];
}

// ---------------- K2b: scan bucket totals -> bucket_start ----------------

__global__ __launch_bounds__(256) void k_bucket_scan(const int* __restrict__ total,
                                                     int* __restrict__ bucket_start,
                                                     int* __restrict__ row_start) {
    __shared__ int ps[256];
    int t = threadIdx.x;
    int v[4];
    int base = t * 4;
#pragma unroll
    for (int q = 0; q < 4; ++q) v[q] = (base + q < NBUCK) ? total[base + q] : 0;
    ps[t] = v[0] + v[1] + v[2] + v[3];
    __syncthreads();
    for (int o = 1; o < 256; o <<= 1) {
        int u = (t >= o) ? ps[t - o] : 0;
        __syncthreads();
        ps[t] += u;
        __syncthreads();
    }
    int run = (t > 0) ? ps[t - 1] : 0;
#pragma unroll
    for (int q = 0; q < 4; ++q) {
        if (base + q <= NBUCK) bucket_start[base + q] = run;
        run += v[q];
    }
    if (t == 0) row_start[N_NODES] = N_EDGES;
}

// ------- K3 fat kernel: blocks [0,512) scatter edges into buckets; rest do h1 = x@W1 -------

__global__ __launch_bounds__(256) void k_scatter_fat(const int* __restrict__ src,
                                                     const int* __restrict__ dst,
                                                     const int* __restrict__ bucket_start,
                                                     const int* __restrict__ off,
                                                     int* __restrict__ tmp,
                                                     const float* __restrict__ x,
                                                     const float* __restrict__ W1,
                                                     float* __restrict__ h1) {
    __shared__ float smem[IN_C * HID_C + 16 * IN_C];  // 40 KiB (W1 + 16-row x tile)
    int t = threadIdx.x;
    if (blockIdx.x < NBLK_B) {
        // bucket scatter: write window per (block, bucket) is disjoint
        int* cur = (int*)smem;
        for (int b = t; b < NBUCK; b += 256)
            cur[b] = bucket_start[b] + off[blockIdx.x * BSTRIDE + b];
        __syncthreads();
        int base = blockIdx.x * CHUNK, end = base + CHUNK;
#pragma unroll
        for (int it = 0; it < 13; ++it) {
            int i = base + it * 256 + t;
            if (i < end) {
                int s = src[i], d = dst[i];
                int b = d >> 7;
                int p = atomicAdd(&cur[b], 1);
                tmp[p] = (s << 7) | (d & 127);
            }
        }
    } else {
        // h1 = x @ W1 over 256 rows per block; W1 staged once; 4 rows/wave register-blocked
        float* Ws = smem;                 // 8192 floats
        float* xs = smem + IN_C * HID_C;  // 2048 floats: 16 rows x 128
        int rowbase = (blockIdx.x - NBLK_B) * GROWS;
        for (int j = t; j < IN_C * HID_C; j += 256) Ws[j] = W1[j];
        int wave = t >> 6, lane = t & 63;
        int rl0 = wave * 4;
        for (int it = 0; it < 16; ++it) {
            int r0 = rowbase + it * 16;
            __syncthreads();  // covers Ws staging (first iter) and xs reuse (later iters)
#pragma unroll
            for (int q = 0; q < 8; ++q) {
                int idx = q * 256 + t;           // 0..2047
                int rl = idx >> 7, k = idx & 127;
                int row = r0 + rl;
                xs[idx] = (row < N_NODES) ? x[row * IN_C + k] : 0.f;
            }
            __syncthreads();
            float a0 = 0.f, a1 = 0.f, a2 = 0.f, a3 = 0.f;
#pragma unroll 4
            for (int k = 0; k < IN_C; ++k) {
                float w = Ws[k * HID_C + lane];
                a0 += xs[(rl0 + 0) * IN_C + k] * w;
                a1 += xs[(rl0 + 1) * IN_C + k] * w;
                a2 += xs[(rl0 + 2) * IN_C + k] * w;
                a3 += xs[(rl0 + 3) * IN_C + k] * w;
            }
            int row = r0 + rl0;
            if (row + 0 < N_NODES) h1[(row + 0) * HID_C + lane] = a0;
            if (row + 1 < N_NODES) h1[(row + 1) * HID_C + lane] = a1;
            if (row + 2 < N_NODES) h1[(row + 2) * HID_C + lane] = a2;
            if (row + 3 < N_NODES) h1[(row + 3) * HID_C + lane] = a3;
        }
    }
}

// ------- K4: per-bucket CSR build (LDS hist + scan + cursors), emits row_start/dinv/eidx -------

__global__ __launch_bounds__(256) void k_csr_build(const int* __restrict__ bucket_start,
                                                   const int* __restrict__ tmp,
                                                   int* __restrict__ row_start,
                                                   int* __restrict__ eidx,
                                                   float* __restrict__ dinv) {
    __shared__ int h[128];
    __shared__ int cur[128];
    int b = blockIdx.x, t = threadIdx.x;
    int e0 = bucket_start[b], e1 = bucket_start[b + 1];
    if (t < 128) h[t] = 0;
    int pk[MAXPT];
#pragma unroll
    for (int k = 0; k < MAXPT; ++k) {
        int i = e0 + k * 256 + t;
        pk[k] = (i < e1) ? tmp[i] : -1;
    }
    __syncthreads();
#pragma unroll
    for (int k = 0; k < MAXPT; ++k)
        if (pk[k] >= 0) atomicAdd(&h[pk[k] & 127], 1);
    for (int i = e0 + MAXPT * 256 + t; i < e1; i += 256)  // safety tail (never expected)
        atomicAdd(&h[tmp[i] & 127], 1);
    __syncthreads();
    int d0 = (t < 128) ? h[t] : 0;
    // inclusive scan over 128 entries
    for (int o = 1; o < 128; o <<= 1) {
        int u = (t >= o && t < 128) ? h[t - o] : 0;
        __syncthreads();
        if (t < 128) h[t] += u;
        __syncthreads();
    }
    int g = b * 128 + t;
    if (t < 128 && g < N_NODES) {
        int ex = h[t] - d0;
        row_start[g] = e0 + ex;
        cur[t]       = e0 + ex;
        dinv[g] = rsqrtf((float)(d0 + 1));  // +1 self loop
    }
    __syncthreads();
#pragma unroll
    for (int k = 0; k < MAXPT; ++k)
        if (pk[k] >= 0) {
            int p = atomicAdd(&cur[pk[k] & 127], 1);
            eidx[p] = pk[k] >> 7;
        }
    for (int i = e0 + MAXPT * 256 + t; i < e1; i += 256) {
        int v = tmp[i];
        int p = atomicAdd(&cur[v & 127], 1);
        eidx[p] = v >> 7;
    }
}

// ------- gather layer 1: a1 = relu(dinv_i*(dinv_i*h1_i + sum_j dinv_j*h1_j) + b1) -------

__global__ __launch_bounds__(256) void k_gather1(const int* __restrict__ row_start,
                                                 const int* __restrict__ eidx,
                                                 const float* __restrict__ h1,
                                                 const float* __restrict__ dinv,
                                                 const float* __restrict__ b1,
                                                 float* __restrict__ a1) {
    int tid  = threadIdx.x;
    int lane = tid & 63;
    int node = blockIdx.x * 4 + (tid >> 6);
    if (node >= N_NODES) return;

    float dn = dinv[node];
    int rs = row_start[node];
    int re = row_start[node + 1];
    float acc = dn * h1[node * HID_C + lane];  // self loop
    int j = rs;
    for (; j + 3 < re; j += 4) {
        int s0 = eidx[j], s1 = eidx[j + 1], s2 = eidx[j + 2], s3 = eidx[j + 3];
        float g0 = dinv[s0], g1 = dinv[s1], g2 = dinv[s2], g3 = dinv[s3];
        float v0 = h1[s0 * HID_C + lane];
        float v1 = h1[s1 * HID_C + lane];
        float v2 = h1[s2 * HID_C + lane];
        float v3 = h1[s3 * HID_C + lane];
        acc += g0 * v0 + g1 * v1 + g2 * v2 + g3 * v3;
    }
    for (; j < re; ++j) acc += dinv[eidx[j]] * h1[eidx[j] * HID_C + lane];

    float v = dn * acc + b1[lane];
    a1[node * HID_C + lane] = fmaxf(v, 0.f);
}

// ---------------- layer 2 GEMM: hs2 = dinv * (a1 @ W2) ----------------

__global__ __launch_bounds__(256) void k_gemm2(const float* __restrict__ a1,
                                               const float* __restrict__ W2,
                                               const float* __restrict__ dinv,
                                               float* __restrict__ hs2) {
    __shared__ float Ws[HID_C * OUT_C];  // 8 KiB
    __shared__ float as[8 * HID_C];      // 2 KiB
    int tid = threadIdx.x;
    for (int j = tid; j < HID_C * OUT_C; j += 256) Ws[j] = W2[j];
    int r = tid >> 5;   // 0..7
    int c = tid & 31;   // 0..31
    int row0 = blockIdx.x * 8;
    as[tid]       = a1[row0 * HID_C + tid];
    as[tid + 256] = a1[row0 * HID_C + tid + 256];
    __syncthreads();
    float sum = 0.f;
#pragma unroll
    for (int k = 0; k < HID_C; ++k) sum += as[r * HID_C + k] * Ws[k * OUT_C + c];
    int row = row0 + r;
    hs2[row * OUT_C + c] = dinv[row] * sum;
}

// ------- gather layer 2 + epilogue: out = dinv*(hs2[i] + sum_j hs2[src_j]) + b2 -------

__global__ __launch_bounds__(256) void k_gather2(const int* __restrict__ row_start,
                                                 const int* __restrict__ eidx,
                                                 const float* __restrict__ hs2,
                                                 const float* __restrict__ dinv,
                                                 const float* __restrict__ b2,
                                                 float* __restrict__ out) {
    int tid  = threadIdx.x;
    int lane = tid & 63;
    int half = lane >> 5;   // 0 or 1
    int c    = lane & 31;
    int node = blockIdx.x * 4 + (tid >> 6);
    if (node >= N_NODES) return;

    int rs = row_start[node];
    int re = row_start[node + 1];
    float acc = (half == 0) ? hs2[node * OUT_C + c] : 0.f;  // self loop
    int j = rs + half;
    for (; j + 3 < re; j += 4) {
        int s0 = eidx[j], s1 = eidx[j + 2];
        float v0 = hs2[s0 * OUT_C + c];
        float v1 = hs2[s1 * OUT_C + c];
        acc += v0 + v1;
    }
    for (; j < re; j += 2) acc += hs2[eidx[j] * OUT_C + c];

    acc += __shfl_xor(acc, 32);
    if (half == 0) out[node * OUT_C + c] = dinv[node] * acc + b2[c];
}

extern "C" void kernel_launch(void* const* d_in, const int* in_sizes, int n_in,
                              void* d_out, int out_size, void* d_ws, size_t ws_size,
                              hipStream_t stream) {
    const float* x  = (const float*)d_in[0];
    const int* ei   = (const int*)d_in[1];   // [2, E]: src then dst
    const float* W1 = (const float*)d_in[2];
    const float* b1 = (const float*)d_in[3];
    const float* W2 = (const float*)d_in[4];
    const float* b2 = (const float*)d_in[5];
    float* out = (float*)d_out;

    const int* src = ei;
    const int* dst = ei + N_EDGES;

    // workspace layout (bytes), total ~62.6 MB
    char* ws = (char*)d_ws;
    int*   row_start    = (int*)(ws + 0);           //   400,128 (N+1 ints)
    float* dinv         = (float*)(ws + 400128);    //   400,128
    int*   bucket_start = (int*)(ws + 800256);      //     4,096
    int*   total        = (int*)(ws + 804352);      //     4,096
    int*   bcnt         = (int*)(ws + 808448);      // 2,097,152
    int*   off          = (int*)(ws + 2905600);     // 2,097,152
    int*   eidx         = (int*)(ws + 5002752);     // 6,400,000
    float* h1           = (float*)(ws + 11402752);  // 25,600,000
    float* a1           = (float*)(ws + 37002752);  // 25,600,000
    int*   tmp          = (int*)(ws + 37002752);    // overlays a1 (dead before gather1 writes a1)
    float* hs2          = h1;                       // reuse (h1 dead after gather1)

    k_bucket_count<<<NBLK_B, 256, 0, stream>>>(dst, bcnt);
    k_col_scan<<<NBUCK, 256, 0, stream>>>(bcnt, off, total);
    k_bucket_scan<<<1, 256, 0, stream>>>(total, bucket_start, row_start);

    k_scatter_fat<<<NBLK_B + GEMM_BLKS, 256, 0, stream>>>(src, dst, bucket_start, off,
                                                          tmp, x, W1, h1);
    k_csr_build<<<NBUCK, 256, 0, stream>>>(bucket_start, tmp, row_start, eidx, dinv);

    k_gather1<<<N_NODES / 4, 256, 0, stream>>>(row_start, eidx, h1, dinv, b1, a1);

    k_gemm2<<<N_NODES / 8, 256, 0, stream>>>(a1, W2, dinv, hs2);
    k_gather2<<<N_NODES / 4, 256, 0, stream>>>(row_start, eidx, hs2, dinv, b2, out);
}

// Round 6
// 223.630 us; speedup vs baseline: 1.3417x; 1.3417x over previous
//
#include <hip/hip_runtime.h>

#define N_NODES 100000
#define N_EDGES 1600000
#define IN_C 128
#define HID_C 64
#define OUT_C 32

#define NBUCK 782        // ceil(100000 / 128) buckets of 128 nodes
#define NBLK_B 1024      // edge-chunk blocks for bucket count/scatter
#define CHUNK 1563       // ceil(N_EDGES / NBLK_B)
#define BSTRIDE 1024     // padded stride for bcnt/off tables
#define MAXPT 12         // per-thread reg capacity in CSR build (3072/bucket)

#define GROWS 16         // rows per GEMM block
#define GEMM_BLKS 6250   // N_NODES / GROWS (exact)

typedef unsigned int uint;
typedef unsigned short ushort;

__device__ inline ushort f2bf(float f) {   // RNE float->bf16
    uint u = __float_as_uint(f);
    u += 0x7fff + ((u >> 16) & 1);
    return (ushort)(u >> 16);
}

// ---------------- K1: per-block coarse bucket histogram (LDS atomics only) ----------------

__global__ __launch_bounds__(256) void k_bucket_count(const int* __restrict__ dst,
                                                      int* __restrict__ bcnt) {
    __shared__ int h[NBUCK];
    int t = threadIdx.x;
    for (int b = t; b < NBUCK; b += 256) h[b] = 0;
    __syncthreads();
    int base = blockIdx.x * CHUNK;
    int end = base + CHUNK; if (end > N_EDGES) end = N_EDGES;
#pragma unroll
    for (int it = 0; it < 7; ++it) {
        int i = base + it * 256 + t;
        if (i < end) atomicAdd(&h[dst[i] >> 7], 1);
    }
    __syncthreads();
    for (int b = t; b < NBUCK; b += 256) bcnt[blockIdx.x * BSTRIDE + b] = h[b];
}

// ---------------- K2a: per-bucket column scan over 1024 blocks -> off, total ----------------

__global__ __launch_bounds__(256) void k_col_scan(const int* __restrict__ bcnt,
                                                  int* __restrict__ off,
                                                  int* __restrict__ total) {
    __shared__ int v[NBLK_B];
    __shared__ int ps[256];
    int t = threadIdx.x, b = blockIdx.x;
#pragma unroll
    for (int q = 0; q < NBLK_B / 256; ++q)
        v[q * 256 + t] = bcnt[(q * 256 + t) * BSTRIDE + b];
    __syncthreads();
    int l0 = v[t * 4], l1 = v[t * 4 + 1], l2 = v[t * 4 + 2], l3 = v[t * 4 + 3];
    ps[t] = l0 + l1 + l2 + l3;
    __syncthreads();
    for (int o = 1; o < 256; o <<= 1) {
        int u = (t >= o) ? ps[t - o] : 0;
        __syncthreads();
        ps[t] += u;
        __syncthreads();
    }
    int ex = (t > 0) ? ps[t - 1] : 0;
    off[(t * 4 + 0) * BSTRIDE + b] = ex; ex += l0;
    off[(t * 4 + 1) * BSTRIDE + b] = ex; ex += l1;
    off[(t * 4 + 2) * BSTRIDE + b] = ex; ex += l2;
    off[(t * 4 + 3) * BSTRIDE + b] = ex; ex += l3;
    if (t == 255) total[b] = ex;
}

// ---------------- K2b: scan bucket totals -> bucket_start ----------------

__global__ __launch_bounds__(256) void k_bucket_scan(const int* __restrict__ total,
                                                     int* __restrict__ bucket_start,
                                                     int* __restrict__ row_start) {
    __shared__ int ps[256];
    int t = threadIdx.x;
    int v[4];
    int base = t * 4;
#pragma unroll
    for (int q = 0; q < 4; ++q) v[q] = (base + q < NBUCK) ? total[base + q] : 0;
    ps[t] = v[0] + v[1] + v[2] + v[3];
    __syncthreads();
    for (int o = 1; o < 256; o <<= 1) {
        int u = (t >= o) ? ps[t - o] : 0;
        __syncthreads();
        ps[t] += u;
        __syncthreads();
    }
    int run = (t > 0) ? ps[t - 1] : 0;
#pragma unroll
    for (int q = 0; q < 4; ++q) {
        if (base + q <= NBUCK) bucket_start[base + q] = run;
        run += v[q];
    }
    if (t == 0) row_start[N_NODES] = N_EDGES;
}

// ------- K3 fat kernel: blocks [0,1024) scatter edges into buckets; rest do h1 = x@W1 -------
// LDS kept at 8 KiB so both branches run at high occupancy.

__global__ __launch_bounds__(256) void k_scatter_fat(const int* __restrict__ src,
                                                     const int* __restrict__ dst,
                                                     const int* __restrict__ bucket_start,
                                                     const int* __restrict__ off,
                                                     int* __restrict__ tmp,
                                                     const float* __restrict__ x,
                                                     const float* __restrict__ W1,
                                                     ushort* __restrict__ h1b) {
    __shared__ float smem[GROWS * IN_C];  // 8 KiB
    int t = threadIdx.x;
    if (blockIdx.x < NBLK_B) {
        // bucket scatter: write window per (block, bucket) is disjoint
        int* cur = (int*)smem;
        for (int b = t; b < NBUCK; b += 256)
            cur[b] = bucket_start[b] + off[blockIdx.x * BSTRIDE + b];
        __syncthreads();
        int base = blockIdx.x * CHUNK;
        int end = base + CHUNK; if (end > N_EDGES) end = N_EDGES;
#pragma unroll
        for (int it = 0; it < 7; ++it) {
            int i = base + it * 256 + t;
            if (i < end) {
                int s = src[i], d = dst[i];
                int b = d >> 7;
                int p = atomicAdd(&cur[b], 1);
                tmp[p] = (s << 7) | (d & 127);
            }
        }
    } else {
        // h1 = x @ W1, 16 rows/block; x tile in LDS, W1 streamed from L2
        int rowbase = (blockIdx.x - NBLK_B) * GROWS;
#pragma unroll
        for (int q = 0; q < 8; ++q)
            smem[q * 256 + t] = x[rowbase * IN_C + q * 256 + t];
        __syncthreads();
        int wave = t >> 6, lane = t & 63;
        int rl0 = wave * 4;
        float a0 = 0.f, a1 = 0.f, a2 = 0.f, a3 = 0.f;
#pragma unroll 8
        for (int k = 0; k < IN_C; ++k) {
            float w = W1[k * HID_C + lane];
            a0 += smem[(rl0 + 0) * IN_C + k] * w;
            a1 += smem[(rl0 + 1) * IN_C + k] * w;
            a2 += smem[(rl0 + 2) * IN_C + k] * w;
            a3 += smem[(rl0 + 3) * IN_C + k] * w;
        }
        int row = rowbase + rl0;
        h1b[(row + 0) * HID_C + lane] = f2bf(a0);
        h1b[(row + 1) * HID_C + lane] = f2bf(a1);
        h1b[(row + 2) * HID_C + lane] = f2bf(a2);
        h1b[(row + 3) * HID_C + lane] = f2bf(a3);
    }
}

// ------- K4: per-bucket CSR build (LDS hist + scan + cursors), emits row_start/dinv/eidx -------

__global__ __launch_bounds__(256) void k_csr_build(const int* __restrict__ bucket_start,
                                                   const int* __restrict__ tmp,
                                                   int* __restrict__ row_start,
                                                   int* __restrict__ eidx,
                                                   float* __restrict__ dinv) {
    __shared__ int h[128];
    __shared__ int cur[128];
    int b = blockIdx.x, t = threadIdx.x;
    int e0 = bucket_start[b], e1 = bucket_start[b + 1];
    if (t < 128) h[t] = 0;
    int pk[MAXPT];
#pragma unroll
    for (int k = 0; k < MAXPT; ++k) {
        int i = e0 + k * 256 + t;
        pk[k] = (i < e1) ? tmp[i] : -1;
    }
    __syncthreads();
#pragma unroll
    for (int k = 0; k < MAXPT; ++k)
        if (pk[k] >= 0) atomicAdd(&h[pk[k] & 127], 1);
    for (int i = e0 + MAXPT * 256 + t; i < e1; i += 256)  // safety tail
        atomicAdd(&h[tmp[i] & 127], 1);
    __syncthreads();
    int d0 = (t < 128) ? h[t] : 0;
    for (int o = 1; o < 128; o <<= 1) {
        int u = (t >= o && t < 128) ? h[t - o] : 0;
        __syncthreads();
        if (t < 128) h[t] += u;
        __syncthreads();
    }
    int g = b * 128 + t;
    if (t < 128 && g < N_NODES) {
        int ex = h[t] - d0;
        row_start[g] = e0 + ex;
        cur[t]       = e0 + ex;
        dinv[g] = rsqrtf((float)(d0 + 1));  // +1 self loop
    }
    __syncthreads();
#pragma unroll
    for (int k = 0; k < MAXPT; ++k)
        if (pk[k] >= 0) {
            int p = atomicAdd(&cur[pk[k] & 127], 1);
            eidx[p] = pk[k] >> 7;
        }
    for (int i = e0 + MAXPT * 256 + t; i < e1; i += 256) {
        int v = tmp[i];
        int p = atomicAdd(&cur[v & 127], 1);
        eidx[p] = v >> 7;
    }
}

// ------- gather layer 1 (bf16 h1): a1 = relu(dn*(dn*h_i + sum_j dinv_j*h_j) + b1) -------
// 32 lanes per node; lane owns one bf16x2 channel pair.

__global__ __launch_bounds__(256) void k_gather1(const int* __restrict__ row_start,
                                                 const int* __restrict__ eidx,
                                                 const uint* __restrict__ h1u,
                                                 const float* __restrict__ dinv,
                                                 const float* __restrict__ b1,
                                                 float* __restrict__ a1) {
    int tid = threadIdx.x;
    int sub = tid & 31;
    int node = blockIdx.x * 8 + (tid >> 5);
    if (node >= N_NODES) return;

    float dn = dinv[node];
    int rs = row_start[node];
    int re = row_start[node + 1];
    uint su = h1u[node * 32 + sub];
    float accx = dn * __uint_as_float(su << 16);
    float accy = dn * __uint_as_float(su & 0xffff0000u);
    int j = rs;
    for (; j + 3 < re; j += 4) {
        int s0 = eidx[j], s1 = eidx[j + 1], s2 = eidx[j + 2], s3 = eidx[j + 3];
        float g0 = dinv[s0], g1 = dinv[s1], g2 = dinv[s2], g3 = dinv[s3];
        uint u0 = h1u[s0 * 32 + sub];
        uint u1 = h1u[s1 * 32 + sub];
        uint u2 = h1u[s2 * 32 + sub];
        uint u3 = h1u[s3 * 32 + sub];
        accx += g0 * __uint_as_float(u0 << 16) + g1 * __uint_as_float(u1 << 16)
              + g2 * __uint_as_float(u2 << 16) + g3 * __uint_as_float(u3 << 16);
        accy += g0 * __uint_as_float(u0 & 0xffff0000u) + g1 * __uint_as_float(u1 & 0xffff0000u)
              + g2 * __uint_as_float(u2 & 0xffff0000u) + g3 * __uint_as_float(u3 & 0xffff0000u);
    }
    for (; j < re; ++j) {
        int s = eidx[j];
        float g = dinv[s];
        uint u = h1u[s * 32 + sub];
        accx += g * __uint_as_float(u << 16);
        accy += g * __uint_as_float(u & 0xffff0000u);
    }
    float2 bb = *(const float2*)&b1[sub * 2];
    float vx = fmaxf(dn * accx + bb.x, 0.f);
    float vy = fmaxf(dn * accy + bb.y, 0.f);
    *(float2*)&a1[node * HID_C + sub * 2] = make_float2(vx, vy);
}

// ---------------- layer 2 GEMM: hs2 = dinv * (a1 @ W2) ----------------

__global__ __launch_bounds__(256) void k_gemm2(const float* __restrict__ a1,
                                               const float* __restrict__ W2,
                                               const float* __restrict__ dinv,
                                               float* __restrict__ hs2) {
    __shared__ float Ws[HID_C * OUT_C];  // 8 KiB
    __shared__ float as[8 * HID_C];      // 2 KiB
    int tid = threadIdx.x;
    for (int j = tid; j < HID_C * OUT_C; j += 256) Ws[j] = W2[j];
    int r = tid >> 5;   // 0..7
    int c = tid & 31;   // 0..31
    int row0 = blockIdx.x * 8;
    as[tid]       = a1[row0 * HID_C + tid];
    as[tid + 256] = a1[row0 * HID_C + tid + 256];
    __syncthreads();
    float sum = 0.f;
#pragma unroll
    for (int k = 0; k < HID_C; ++k) sum += as[r * HID_C + k] * Ws[k * OUT_C + c];
    int row = row0 + r;
    hs2[row * OUT_C + c] = dinv[row] * sum;
}

// ------- gather layer 2 + epilogue: out = dinv*(hs2[i] + sum_j hs2[src_j]) + b2 -------

__global__ __launch_bounds__(256) void k_gather2(const int* __restrict__ row_start,
                                                 const int* __restrict__ eidx,
                                                 const float* __restrict__ hs2,
                                                 const float* __restrict__ dinv,
                                                 const float* __restrict__ b2,
                                                 float* __restrict__ out) {
    int tid  = threadIdx.x;
    int lane = tid & 63;
    int half = lane >> 5;   // 0 or 1
    int c    = lane & 31;
    int node = blockIdx.x * 4 + (tid >> 6);
    if (node >= N_NODES) return;

    int rs = row_start[node];
    int re = row_start[node + 1];
    float acc = (half == 0) ? hs2[node * OUT_C + c] : 0.f;  // self loop
    int j = rs + half;
    for (; j + 3 < re; j += 4) {
        int s0 = eidx[j], s1 = eidx[j + 2];
        float v0 = hs2[s0 * OUT_C + c];
        float v1 = hs2[s1 * OUT_C + c];
        acc += v0 + v1;
    }
    for (; j < re; j += 2) acc += hs2[eidx[j] * OUT_C + c];

    acc += __shfl_xor(acc, 32);
    if (half == 0) out[node * OUT_C + c] = dinv[node] * acc + b2[c];
}

extern "C" void kernel_launch(void* const* d_in, const int* in_sizes, int n_in,
                              void* d_out, int out_size, void* d_ws, size_t ws_size,
                              hipStream_t stream) {
    const float* x  = (const float*)d_in[0];
    const int* ei   = (const int*)d_in[1];   // [2, E]: src then dst
    const float* W1 = (const float*)d_in[2];
    const float* b1 = (const float*)d_in[3];
    const float* W2 = (const float*)d_in[4];
    const float* b2 = (const float*)d_in[5];
    float* out = (float*)d_out;

    const int* src = ei;
    const int* dst = ei + N_EDGES;

    // workspace layout (bytes), total ~54.0 MB
    char* ws = (char*)d_ws;
    int*    row_start    = (int*)(ws + 0);            //   400,128 (N+1 ints)
    float*  dinv         = (float*)(ws + 400128);     //   400,128
    int*    bucket_start = (int*)(ws + 800256);       //     4,096
    int*    total        = (int*)(ws + 804352);       //     4,096
    int*    bcnt         = (int*)(ws + 808448);       // 4,194,304
    int*    off          = (int*)(ws + 5002752);      // 4,194,304
    int*    eidx         = (int*)(ws + 9197056);      // 6,400,000
    ushort* h1b          = (ushort*)(ws + 15597056);  // 12,800,000 (bf16)
    float*  a1           = (float*)(ws + 28397056);   // 25,600,000
    int*    tmp          = (int*)(ws + 28397056);     // overlays a1 (dead before gather1)
    float*  hs2          = (float*)(ws + 15597056);   // overlays h1b (dead after gather1)

    k_bucket_count<<<NBLK_B, 256, 0, stream>>>(dst, bcnt);
    k_col_scan<<<NBUCK, 256, 0, stream>>>(bcnt, off, total);
    k_bucket_scan<<<1, 256, 0, stream>>>(total, bucket_start, row_start);

    k_scatter_fat<<<NBLK_B + GEMM_BLKS, 256, 0, stream>>>(src, dst, bucket_start, off,
                                                          tmp, x, W1, h1b);
    k_csr_build<<<NBUCK, 256, 0, stream>>>(bucket_start, tmp, row_start, eidx, dinv);

    k_gather1<<<(N_NODES + 7) / 8, 256, 0, stream>>>(row_start, eidx, (const uint*)h1b,
                                                     dinv, b1, a1);

    k_gemm2<<<N_NODES / 8, 256, 0, stream>>>(a1, W2, dinv, hs2);
    k_gather2<<<N_NODES / 4, 256, 0, stream>>>(row_start, eidx, hs2, dinv, b2, out);
}